// Round 11
// baseline (245.321 us; speedup 1.0000x reference)
//
#include <hip/hip_runtime.h>
#include <hip/hip_fp16.h>

#define D 128
#define HB 128        // histogram blocks per role (edge-partitioned)
#define HT 1024       // threads per histogram block
#define WMAX 12800    // LDS histogram words (4 nodes/word, byte counters)

struct alignas(16) H8 { __half2 h[4]; };
typedef _Float16 v8h __attribute__((ext_vector_type(8)));
typedef float v4f __attribute__((ext_vector_type(4)));

// ---------------------------------------------------------------------------
// R20 = R9 (237.7us best) + R7's mega-structure, aggregate UNTOUCHED.
// R7 post-mortem: mega(hist||gemm1) + merged fill saved ~23us of chain time
// (rest 151->128) but the WEIGHTED aggregate sibling poisoned regalloc of
// all three aggregate dispatches (29.5 -> 45.4us each). R10 defers onorm
// WITHOUT touching the aggregate: gemm1-raw writes fp32 y1raw in the mega
// dispatch (concurrent with hist), and a 'scale' role in the finalize||fill
// dispatch streams y1 = fp16(y1raw * onorm[row]) — numerically identical to
// R9's epilogue (single fp16 rounding of an fp32 product). Aggregate and
// gemm_mfma are byte-identical to R9; same template instantiation set.
// Chain: 9 -> 8 dispatches; gemm1 leaves the serial critical path.
// ---------------------------------------------------------------------------

// ---------------------------------------------------------------------------
// MEGA: hist (blocks [0,2HB)) + W-prep W2/W3 ([2HB,2HB+2)) + gemm1-raw
// (y1raw = x@W1, fp32, NO onorm). Dynamic LDS 69632B: hist uses 50000B as
// lcnt; gemm uses sA/sB (2x128x136 halves).
// ---------------------------------------------------------------------------
__global__ __launch_bounds__(HT) void mega_kernel(const int* __restrict__ src,
                                                  const int* __restrict__ dst,
                                                  unsigned* __restrict__ partial_out,
                                                  unsigned* __restrict__ partial_in,
                                                  unsigned char* __restrict__ lrank,
                                                  const float* __restrict__ W1,
                                                  const float* __restrict__ W2,
                                                  const float* __restrict__ W3,
                                                  _Float16* __restrict__ wt,
                                                  const float* __restrict__ x,
                                                  float* __restrict__ y1raw,
                                                  int nE, int W, int epb, int nrows) {
    extern __shared__ char smem[];
    const int t = threadIdx.x;

    if ((int)blockIdx.x < 2 * HB) {
        // ---- hist role (R8-proven) ----
        unsigned* lcnt = (unsigned*)smem;
        const bool is_dst = (blockIdx.x < HB);
        const int b = is_dst ? blockIdx.x : (blockIdx.x - HB);
        for (int i = t; i < W; i += HT) lcnt[i] = 0;
        __syncthreads();
        const int e0 = b * epb;
        const int e1 = min(nE, e0 + epb);
        if (is_dst) {
            for (int e = e0 + t; e < e1; e += HT) {
                const int d = dst[e];
                const unsigned sh = (unsigned)(d & 3) * 8u;
                const unsigned old = atomicAdd(&lcnt[d >> 2], 1u << sh);
                lrank[e] = (unsigned char)((old >> sh) & 0xffu);
            }
        } else {
            for (int e = e0 + t; e < e1; e += HT) {
                const int s = src[e];
                atomicAdd(&lcnt[s >> 2], 1u << ((unsigned)(s & 3) * 8u));
            }
        }
        __syncthreads();
        unsigned* g = (is_dst ? partial_in : partial_out) + (size_t)b * W;
        for (int i = t; i < W; i += HT) g[i] = lcnt[i];
        return;
    }

    if ((int)blockIdx.x < 2 * HB + 2) {
        // ---- W-prep role: transpose W2/W3 to fp16 [n][k] ----
        const int l = blockIdx.x - 2 * HB + 1;          // 1 or 2
        const float* Wsrc = (l == 1) ? W2 : W3;
        _Float16* o = wt + (size_t)l * D * D;
        for (int i = t; i < D * D; i += HT) {
            const int k = i >> 7, n = i & 127;
            o[n * D + k] = (_Float16)Wsrc[i];
        }
        return;
    }

    // ---- gemm1-raw role: y1raw = x@W1 (fp32 out), 128x128 tile ----
    _Float16* sA = (_Float16*)smem;
    _Float16* sB = sA + 128 * 136;
    const int blk = blockIdx.x - (2 * HB + 2);
    const int row0 = blk * 128;
    const int rr = t >> 4;      // 64 staging rows per pass
    const int c8 = t & 15;
#pragma unroll
    for (int pass = 0; pass < 2; ++pass) {
        const int row = pass * 64 + rr;
        // B: sB[n=row][k] = W1[k][n]  (strided f32 reads; L2-warm after blk 0)
#pragma unroll
        for (int j = 0; j < 8; ++j)
            sB[row * 136 + c8 * 8 + j] = (_Float16)W1[(size_t)(c8 * 8 + j) * D + row];
        const int grow = row0 + row;
        float4 u0 = make_float4(0.f, 0.f, 0.f, 0.f);
        float4 u1 = u0;
        if (grow < nrows) {
            const float* ap = x + (size_t)grow * D + c8 * 8;
            u0 = ((const float4*)ap)[0];
            u1 = ((const float4*)ap)[1];
        }
        v8h hv;
        hv[0] = (_Float16)u0.x; hv[1] = (_Float16)u0.y;
        hv[2] = (_Float16)u0.z; hv[3] = (_Float16)u0.w;
        hv[4] = (_Float16)u1.x; hv[5] = (_Float16)u1.y;
        hv[6] = (_Float16)u1.z; hv[7] = (_Float16)u1.w;
        *(v8h*)&sA[row * 136 + c8 * 8] = hv;
    }
    __syncthreads();

    const int w = t >> 6;       // 16 waves
    const int lane = t & 63;
    const int m16 = lane & 15;
    const int quad = lane >> 4;
    const int rt = w >> 1;      // row-tile 0..7
    const int ch = w & 1;       // col half 0..1

    v4f c[4];
#pragma unroll
    for (int ct = 0; ct < 4; ++ct) c[ct] = (v4f){0.f, 0.f, 0.f, 0.f};

#pragma unroll
    for (int ks = 0; ks < 4; ++ks) {
        const v8h a = *(const v8h*)&sA[(rt * 16 + m16) * 136 + ks * 32 + quad * 8];
#pragma unroll
        for (int ct = 0; ct < 4; ++ct) {
            const v8h b = *(const v8h*)&sB[((ch * 4 + ct) * 16 + m16) * 136 + ks * 32 + quad * 8];
            c[ct] = __builtin_amdgcn_mfma_f32_16x16x32_f16(a, b, c[ct], 0, 0, 0);
        }
    }

#pragma unroll
    for (int r = 0; r < 4; ++r) {
        const int row = row0 + rt * 16 + quad * 4 + r;
        if (row < nrows) {
#pragma unroll
            for (int ct = 0; ct < 4; ++ct) {
                const int col = (ch * 4 + ct) * 16 + m16;
                y1raw[(size_t)row * D + col] = c[ct][r];
            }
        }
    }
}

// ---------------------------------------------------------------------------
// Reduce 128 partials per node-word + (dst role) block-local exclusive scan
// (R9-proven). dst blocks: offs_in, cnt_in, rpp, bsum[block]. out blocks:
// cnt_out. Block = 256 threads covers 1024 consecutive nodes.
// ---------------------------------------------------------------------------
__global__ __launch_bounds__(256) void reduce_scan_kernel(const unsigned* __restrict__ partial_out,
                                                          const unsigned* __restrict__ partial_in,
                                                          unsigned* __restrict__ offs_in,
                                                          int* __restrict__ cnt_out,
                                                          int* __restrict__ cnt_in,
                                                          int* __restrict__ rpp,
                                                          int* __restrict__ bsum,
                                                          int W, int n, int nbW) {
    const int t = threadIdx.x;
    if ((int)blockIdx.x >= nbW) {
        // ---- out-degree role (no barriers) ----
        const int w = (blockIdx.x - nbW) * 256 + t;
        if (w >= W) return;
        unsigned run = 0;
#pragma unroll 16
        for (int b = 0; b < HB; ++b) run += partial_out[(size_t)b * W + w];
        const int n0 = w * 4;
        const int4 c4 = make_int4((int)(run & 0xffu), (int)((run >> 8) & 0xffu),
                                  (int)((run >> 16) & 0xffu), (int)((run >> 24) & 0xffu));
        if (n0 + 3 < n) {
            *(int4*)&cnt_out[n0] = c4;
        } else {
            const int* cp = &c4.x;
            for (int i = 0; i < 4 && n0 + i < n; ++i) cnt_out[n0 + i] = cp[i];
        }
        return;
    }

    // ---- in-degree role + block scan (all threads alive for barriers) ----
    __shared__ int ws[4];
    const int w = blockIdx.x * 256 + t;
    unsigned run = 0;
    if (w < W) {
#pragma unroll 16
        for (int b = 0; b < HB; ++b) {
            const unsigned c = partial_in[(size_t)b * W + w];
            offs_in[(size_t)b * W + w] = run;
            run += c;
        }
    }
    const int n0 = w * 4;
    int c0 = (int)(run & 0xffu), c1 = (int)((run >> 8) & 0xffu);
    int c2 = (int)((run >> 16) & 0xffu), c3 = (int)((run >> 24) & 0xffu);
    if (n0 >= n)          { c0 = 0; c1 = 0; c2 = 0; c3 = 0; }
    else if (n0 + 1 >= n) { c1 = 0; c2 = 0; c3 = 0; }
    else if (n0 + 2 >= n) { c2 = 0; c3 = 0; }
    else if (n0 + 3 >= n) { c3 = 0; }

    if (w < W) {
        const int4 c4 = make_int4(c0, c1, c2, c3);
        if (n0 + 3 < n) {
            *(int4*)&cnt_in[n0] = c4;
        } else {
            const int* cp = &c4.x;
            for (int i = 0; i < 4 && n0 + i < n; ++i) cnt_in[n0 + i] = cp[i];
        }
    }

    // block-local exclusive scan over 1024 node counts
    const int lane = t & 63;
    const int wid = t >> 6;
    const int T = c0 + c1 + c2 + c3;
    int sincl = T;
#pragma unroll
    for (int off = 1; off < 64; off <<= 1) {
        int u = __shfl_up(sincl, off, 64);
        if (lane >= off) sincl += u;
    }
    if (lane == 63) ws[wid] = sincl;
    __syncthreads();
    int wbase = 0;
#pragma unroll
    for (int j = 0; j < 4; ++j) wbase += (j < wid) ? ws[j] : 0;
    const int excl = wbase + sincl - T;

    if (w < W && n0 < n) {
        const int4 r4 = make_int4(excl, excl + c0, excl + c0 + c1, excl + c0 + c1 + c2);
        if (n0 + 3 < n) {
            *(int4*)&rpp[n0] = r4;
        } else {
            const int* rp4 = &r4.x;
            for (int i = 0; i < 4 && n0 + i < n; ++i) rpp[n0 + i] = rp4[i];
        }
    }
    if (t == 255) bsum[blockIdx.x] = wbase + sincl;   // block total
}

// ---------------------------------------------------------------------------
// FUSED finalize + fill + y1-scale (3 roles, one dispatch).
// finalize [0,nb): rp = rpp + prefix(bsum), onorm, inorm, rp[n]=E.
// fill [nb,nb+fg): derives final rp itself from rpp+bpref (R7-proven),
//   scatters srcs_sorted.
// scale [nb+fg,..): y1 = fp16(y1raw * rsqrt(max(cnt_out[row],1))) —
//   numerically identical to R9's gemm1 epilogue.
// ---------------------------------------------------------------------------
__global__ __launch_bounds__(1024) void finalize_fill_scale_kernel(
    const int* __restrict__ rpp, const int* __restrict__ bsum,
    const int* __restrict__ cnt_out, const int* __restrict__ cnt_in,
    int* __restrict__ rp, float* __restrict__ onorm, float* __restrict__ inorm,
    const int* __restrict__ src, const int* __restrict__ dst,
    const unsigned char* __restrict__ lrank, const unsigned* __restrict__ offs_in,
    int* __restrict__ srcs_sorted,
    const float* __restrict__ y1raw, __half* __restrict__ y1,
    int n, int nb, int nE, int epb, int W, int fg) {
    const int t = threadIdx.x;
    if ((int)blockIdx.x < nb) {
        // ---- finalize role ----
        __shared__ int prefix_s;
        if (t < 64) {
            int v = (t < nb && t < (int)blockIdx.x) ? bsum[t] : 0;
#pragma unroll
            for (int off = 1; off < 64; off <<= 1) v += __shfl_xor(v, off, 64);
            if (t == 0) prefix_s = v;
        }
        __syncthreads();
        const int i = blockIdx.x * 1024 + t;
        if (i < n) {
            rp[i] = rpp[i] + prefix_s;
            onorm[i] = rsqrtf(fmaxf((float)cnt_out[i], 1.0f));
            inorm[i] = rsqrtf(fmaxf((float)cnt_in[i], 1.0f));
        }
        if (blockIdx.x == 0 && t == 0) rp[n] = nE;
        return;
    }

    if ((int)blockIdx.x < nb + fg) {
        // ---- fill role (R7-proven self-derived rp) ----
        __shared__ int bpref[64];    // inclusive scan of bsum
        if (t < 64) {
            int v = (t < nb) ? bsum[t] : 0;
            const int lane = t;
#pragma unroll
            for (int off = 1; off < 64; off <<= 1) {
                int u = __shfl_up(v, off, 64);
                if (lane >= off) v += u;
            }
            bpref[t] = v;
        }
        __syncthreads();
        const int e = (blockIdx.x - nb) * 1024 + t;
        if (e < nE) {
            const int d = dst[e];
            const int b = e / epb;
            const unsigned off =
                (offs_in[(size_t)b * W + (d >> 2)] >> ((unsigned)(d & 3) * 8u)) & 0xffu;
            const int blkd = d >> 10;
            const int rpf = rpp[d] + (blkd ? bpref[blkd - 1] : 0);
            srcs_sorted[rpf + (int)off + (int)lrank[e]] = src[e];
        }
        return;
    }

    // ---- scale role: 8 elements (one H8 chunk) per thread ----
    const int c = (blockIdx.x - nb - fg) * 1024 + t;      // chunk id
    const int nchunks = n * (D / 8);
    if (c < nchunks) {
        const int row = c >> 4;                            // 16 chunks per row
        const float f = rsqrtf(fmaxf((float)cnt_out[row], 1.0f));
        const float4 a0 = ((const float4*)y1raw)[c * 2];
        const float4 a1 = ((const float4*)y1raw)[c * 2 + 1];
        H8 h;
        h.h[0] = __floats2half2_rn(a0.x * f, a0.y * f);
        h.h[1] = __floats2half2_rn(a0.z * f, a0.w * f);
        h.h[2] = __floats2half2_rn(a1.x * f, a1.y * f);
        h.h[3] = __floats2half2_rn(a1.z * f, a1.w * f);
        ((H8*)y1)[c] = h;
    }
}

// ---------------------------------------------------------------------------
// Aggregation v5 (R16/R19-proven, BYTE-IDENTICAL to the 237.7us config):
// row-major 256B wide gather, wave-per-node x4, 8-deep up-front issue,
// fma_mix accumulate. No launch_bounds min-waves; size_t indexing.
// ---------------------------------------------------------------------------
template <bool EPI>
__global__ __launch_bounds__(256) void aggregate_kernel(const __half* __restrict__ xh,
                                                        const float* __restrict__ onorm,
                                                        const float* __restrict__ inorm,
                                                        const float* __restrict__ bias,
                                                        const int* __restrict__ rp,
                                                        const int* __restrict__ srcs,
                                                        __half* __restrict__ agg, int n_nodes) {
    const int node = blockIdx.x * 4 + (threadIdx.x >> 6);
    const int lane = threadIdx.x & 63;
    const int rg = lane >> 4;       // edge slot 0..3
    const int c8 = lane & 15;       // 16B chunk within the 256B row
    if (node >= n_nodes) return;
    const int e0 = rp[node];
    const int e1 = rp[node + 1];
    int e = e0 + rg;

    float acc[8];
#pragma unroll
    for (int j = 0; j < 8; ++j) acc[j] = 0.f;

    // ---- first pass: 8-deep, all loads issued before any use ----
    bool pr[8];
#pragma unroll
    for (int k = 0; k < 8; ++k) pr[k] = (e + 4 * k) < e1;
    int s[8];
#pragma unroll
    for (int k = 0; k < 8; ++k) {
        s[k] = 0;
        if (pr[k]) s[k] = __builtin_nontemporal_load(srcs + e + 4 * k);
    }
    H8 v[8];
#pragma unroll
    for (int k = 0; k < 8; ++k)
        v[k] = ((const H8*)(xh + (size_t)s[k] * D))[c8];
#pragma unroll
    for (int k = 0; k < 8; ++k) {
        if (pr[k]) {
#pragma unroll
            for (int j = 0; j < 4; ++j) {
                acc[2 * j]     = fmaf(__low2float(v[k].h[j]),  1.0f, acc[2 * j]);
                acc[2 * j + 1] = fmaf(__high2float(v[k].h[j]), 1.0f, acc[2 * j + 1]);
            }
        }
    }
    e += 32;

    // ---- rare tail (deg > 32) ----
    while (__any(e < e1)) {
        bool q[4];
        int u[4];
#pragma unroll
        for (int k = 0; k < 4; ++k) {
            q[k] = (e + 4 * k) < e1;
            u[k] = 0;
            if (q[k]) u[k] = __builtin_nontemporal_load(srcs + e + 4 * k);
        }
        H8 w[4];
#pragma unroll
        for (int k = 0; k < 4; ++k)
            w[k] = ((const H8*)(xh + (size_t)u[k] * D))[c8];
#pragma unroll
        for (int k = 0; k < 4; ++k) {
            if (q[k]) {
#pragma unroll
                for (int j = 0; j < 4; ++j) {
                    acc[2 * j]     = fmaf(__low2float(w[k].h[j]),  1.0f, acc[2 * j]);
                    acc[2 * j + 1] = fmaf(__high2float(w[k].h[j]), 1.0f, acc[2 * j + 1]);
                }
            }
        }
        e += 16;
    }

    float r[8];
#pragma unroll
    for (int j = 0; j < 8; ++j) r[j] = acc[j];
#pragma unroll
    for (int off = 16; off < 64; off <<= 1)    // reduce over the 4 edge slots
#pragma unroll
        for (int j = 0; j < 8; ++j) r[j] += __shfl_xor(r[j], off, 64);

    if (rg == 0) {
        if (EPI) {
            const float inm = inorm[node];
            const float onm = onorm[node];
            const float4 bv0 = ((const float4*)bias)[c8 * 2];
            const float4 bv1 = ((const float4*)bias)[c8 * 2 + 1];
            const float* bp0 = &bv0.x;
            const float* bp1 = &bv1.x;
#pragma unroll
            for (int j = 0; j < 4; ++j) {
                r[j]     = fmaxf(fmaf(r[j],     inm, bp0[j]), 0.f) * onm;
                r[j + 4] = fmaxf(fmaf(r[j + 4], inm, bp1[j]), 0.f) * onm;
            }
        }
        H8 h;
#pragma unroll
        for (int j = 0; j < 4; ++j) h.h[j] = __floats2half2_rn(r[2 * j], r[2 * j + 1]);
        ((H8*)(agg + (size_t)node * D))[c8] = h;
    }
}

// ---------------------------------------------------------------------------
// MFMA GEMM for layers 2/3 (R9-proven, byte-identical). 128x128 tile, fp16
// operands, fp32 acc. Epilogue: FULL(*inorm+bias), RELU, OSCALE, OUT16.
// ---------------------------------------------------------------------------
template <bool FULL, bool RELU, bool OSCALE, bool OUT16>
__global__ __launch_bounds__(256) void gemm_mfma_kernel(const __half* __restrict__ Ah,
                                                        const _Float16* __restrict__ Wt,
                                                        const float* __restrict__ bias,
                                                        const float* __restrict__ inorm,
                                                        const float* __restrict__ onorm,
                                                        void* __restrict__ outv, int nrows) {
    __shared__ _Float16 sA[128 * 136];
    __shared__ _Float16 sB[128 * 136];
    const int t = threadIdx.x;
    const int row0 = blockIdx.x * 128;
    const int rr = t >> 4;
    const int c8 = t & 15;

#pragma unroll
    for (int pass = 0; pass < 8; ++pass) {
        const int row = pass * 16 + rr;
        *(float4*)&sB[row * 136 + c8 * 8] = *(const float4*)&Wt[(size_t)row * D + c8 * 8];
        const int grow = row0 + row;
        float4 v = make_float4(0.f, 0.f, 0.f, 0.f);
        if (grow < nrows)
            v = *(const float4*)((const _Float16*)Ah + (size_t)grow * D + c8 * 8);
        *(float4*)&sA[row * 136 + c8 * 8] = v;
    }
    __syncthreads();

    const int w = t >> 6;
    const int lane = t & 63;
    const int m16 = lane & 15;
    const int quad = lane >> 4;

    v4f c[2][8];
#pragma unroll
    for (int rt = 0; rt < 2; ++rt)
#pragma unroll
        for (int ct = 0; ct < 8; ++ct) c[rt][ct] = (v4f){0.f, 0.f, 0.f, 0.f};

#pragma unroll
    for (int ks = 0; ks < 4; ++ks) {
        v8h afr[2], bfr[8];
#pragma unroll
        for (int rt = 0; rt < 2; ++rt)
            afr[rt] = *(const v8h*)&sA[(w * 32 + rt * 16 + m16) * 136 + ks * 32 + quad * 8];
#pragma unroll
        for (int ct = 0; ct < 8; ++ct)
            bfr[ct] = *(const v8h*)&sB[(ct * 16 + m16) * 136 + ks * 32 + quad * 8];
#pragma unroll
        for (int rt = 0; rt < 2; ++rt)
#pragma unroll
            for (int ct = 0; ct < 8; ++ct)
                c[rt][ct] = __builtin_amdgcn_mfma_f32_16x16x32_f16(afr[rt], bfr[ct], c[rt][ct], 0, 0, 0);
    }

#pragma unroll
    for (int rt = 0; rt < 2; ++rt) {
#pragma unroll
        for (int r = 0; r < 4; ++r) {
            const int row = row0 + w * 32 + rt * 16 + quad * 4 + r;
            if (row < nrows) {
                const float inm = FULL ? inorm[row] : 1.0f;
                const float osc = OSCALE ? onorm[row] : 1.0f;
#pragma unroll
                for (int ct = 0; ct < 8; ++ct) {
                    const int col = ct * 16 + m16;
                    float v = c[rt][ct][r];
                    if (FULL) v = fmaf(v, inm, bias[col]);
                    if (RELU) v = fmaxf(v, 0.f);
                    if (OSCALE) v *= osc;
                    if (OUT16) ((__half*)outv)[(size_t)row * D + col] = __float2half(v);
                    else       ((float*)outv)[(size_t)row * D + col] = v;
                }
            }
        }
    }
}

// ---------------------------------------------------------------------------
// Host launch
// ---------------------------------------------------------------------------
extern "C" void kernel_launch(void* const* d_in, const int* in_sizes, int n_in,
                              void* d_out, int out_size, void* d_ws, size_t ws_size,
                              hipStream_t stream) {
    const float* x   = (const float*)d_in[0];
    const int*   src = (const int*)d_in[1];
    const int*   dst = (const int*)d_in[2];
    const float* W1  = (const float*)d_in[3];
    const float* b1  = (const float*)d_in[4];
    const float* W2  = (const float*)d_in[5];
    const float* b2  = (const float*)d_in[6];
    const float* W3  = (const float*)d_in[7];
    const float* b3  = (const float*)d_in[8];

    const int N = in_sizes[0] / D;   // 50000
    const int E = in_sizes[1];       // 800000

    char* p = (char*)d_ws;
    auto alloc = [&](size_t bytes) -> void* {
        void* r = (void*)p;
        p += (bytes + 255) & ~(size_t)255;
        return r;
    };
    int*           cnt_out = (int*)alloc((size_t)N * 4);
    int*           cnt_in  = (int*)alloc((size_t)N * 4);
    int*           rp      = (int*)alloc((size_t)(N + 1) * 4);
    int*           rpp     = (int*)alloc((size_t)(N + 1) * 4);
    int*           bsum    = (int*)alloc(1024 * 4);
    float*         onorm   = (float*)alloc((size_t)N * 4);
    float*         inorm   = (float*)alloc((size_t)N * 4);
    int*           srcs    = (int*)alloc((size_t)E * 4);
    unsigned char* lrank   = (unsigned char*)alloc((size_t)E);
    _Float16*      wt      = (_Float16*)alloc((size_t)3 * D * D * 2);
    float*         y1raw   = (float*)alloc((size_t)N * D * 4);  // 25.6MB fp32
    __half*        hbuf0   = (__half*)alloc((size_t)N * D * 2);  // y1, then h2
    __half*        hbuf1   = (__half*)alloc((size_t)N * D * 2);  // h1
    char*          scratch = (char*)alloc((size_t)3 * HB * ((N + 3) / 4) * 4);  // 19.2MB

    const int W = (N + 3) / 4;              // 12500 packed histogram words
    const int epb = (E + HB - 1) / HB;      // 6250 edges per histogram block
    unsigned* partial_in  = (unsigned*)scratch;
    unsigned* partial_out = partial_in + (size_t)HB * W;
    unsigned* offs_in     = partial_out + (size_t)HB * W;
    __half*   abuf        = (__half*)scratch;                  // a2, a3 (fp16)
    float*    outf        = (float*)d_out;

    const int nb = (N + 1023) / 1024;       // 49
    const int nbW = (W + 255) / 256;        // 49 (same 1024-node granule as nb)
    const int gemmGrid = (N + 127) / 128;   // 391
    const int fillGrid = (E + 1023) / 1024; // 782
    const int scaleGrid = (N * (D / 8) + 1023) / 1024;  // 782
    const int aggGrid = (N + 3) / 4;        // 12500
    const size_t megaLds = (size_t)2 * 128 * 136 * sizeof(_Float16);  // 69632B

    // 1) mega: hist || W-prep(W2,W3) || gemm1-raw (y1raw = x@W1 fp32)
    mega_kernel<<<2 * HB + 2 + gemmGrid, HT, megaLds, stream>>>(
        src, dst, partial_out, partial_in, lrank, W1, W2, W3, wt, x, y1raw,
        E, W, epb, N);
    // 2) reduce partials + block-local scan (rpp, bsum)
    reduce_scan_kernel<<<2 * nbW, 256, 0, stream>>>(partial_out, partial_in, offs_in,
                                                    cnt_out, cnt_in, rpp, bsum, W, N, nbW);
    // 3) finalize || fill || y1-scale
    finalize_fill_scale_kernel<<<nb + fillGrid + scaleGrid, 1024, 0, stream>>>(
        rpp, bsum, cnt_out, cnt_in, rp, onorm, inorm,
        src, dst, lrank, offs_in, srcs, y1raw, hbuf0, N, nb, E, epb, W, fillGrid);

    // 4) Layer 1 aggregate + full epilogue -> h1 fp16
    aggregate_kernel<true><<<aggGrid, 256, 0, stream>>>(
        hbuf0, onorm, inorm, b1, rp, srcs, hbuf1, N);
    // 5-6) Layer 2: a2 = agg(h1) fp16; h2 = relu((a2@W2)*inorm+b2)*onorm -> fp16
    aggregate_kernel<false><<<aggGrid, 256, 0, stream>>>(
        hbuf1, onorm, inorm, b2, rp, srcs, abuf, N);
    gemm_mfma_kernel<true, true, true, true><<<gemmGrid, 256, 0, stream>>>(
        abuf, wt + (size_t)D * D, b2, inorm, onorm, hbuf0, N);
    // 7-8) Layer 3: a3 = agg(h2) fp16; out = (a3@W3)*inorm+b3 -> fp32 d_out
    aggregate_kernel<false><<<aggGrid, 256, 0, stream>>>(
        hbuf0, onorm, inorm, b3, rp, srcs, abuf, N);
    gemm_mfma_kernel<true, false, false, false><<<gemmGrid, 256, 0, stream>>>(
        abuf, wt + (size_t)2 * D * D, b3, inorm, onorm, outf, N);
}

// Round 16
// 235.470 us; speedup vs baseline: 1.0418x; 1.0418x over previous
//
#include <hip/hip_runtime.h>
#include <hip/hip_fp16.h>

#define D 128
#define HB 128        // histogram blocks per role (edge-partitioned)
#define HT 1024       // threads per histogram block
#define WMAX 12800    // LDS histogram words (4 nodes/word, byte counters)

struct alignas(16) H8 { __half2 h[4]; };
typedef _Float16 v8h __attribute__((ext_vector_type(8)));
typedef float v4f __attribute__((ext_vector_type(4)));

// ---------------------------------------------------------------------------
// R21 = R9 (237.7us best) + ZERO-TRAFFIC chain compression.
// R10/R11 lesson: extra N*D passes (fp32 y1raw + scale ~38MB) cost MORE than
// the dispatch-slots they save — chain merges only pay with zero new bytes.
// The one remaining zero-byte merge: finalize becomes a third ROLE inside
// the gemm1_fill dispatch (runs concurrent, not serial):
//  - gemm1 epilogue computes osc = rsqrt(max(cnt_out[row],1)) directly
//    (identical numerics + identical 4B/row read as onorm[row]),
//  - fill derives final rp from rpp + bpref(bsum) itself (R7-proven),
//  - finalize role still writes rp/onorm/inorm for agg1..gemm3.
// Chain: 9 -> 8 dispatches; finalize's ~2us + 1 launch gap leave the
// critical path. Aggregate/gemm_mfma/hist/reduce_scan byte-identical to R9.
// ---------------------------------------------------------------------------

// ---------------------------------------------------------------------------
// Edge-partitioned LDS histogram (R8-proven) + merged W-prep role (3 tail
// blocks transpose W1/2/3 to fp16 [n][k] for MFMA B-frags).
// ---------------------------------------------------------------------------
__global__ __launch_bounds__(HT) void hist_kernel(const int* __restrict__ src,
                                                  const int* __restrict__ dst,
                                                  unsigned* __restrict__ partial_out,
                                                  unsigned* __restrict__ partial_in,
                                                  unsigned char* __restrict__ lrank,
                                                  const float* __restrict__ W1,
                                                  const float* __restrict__ W2,
                                                  const float* __restrict__ W3,
                                                  _Float16* __restrict__ wt,
                                                  int nE, int W, int epb) {
    const int t = threadIdx.x;
    if ((int)blockIdx.x >= 2 * HB) {                 // W-prep role
        const int l = blockIdx.x - 2 * HB;
        const float* Wsrc = (l == 0) ? W1 : ((l == 1) ? W2 : W3);
        _Float16* o = wt + (size_t)l * D * D;
        for (int i = t; i < D * D; i += HT) {
            const int k = i >> 7, n = i & 127;
            o[n * D + k] = (_Float16)Wsrc[i];
        }
        return;
    }
    __shared__ unsigned lcnt[WMAX];
    const bool is_dst = (blockIdx.x < HB);
    const int b = is_dst ? blockIdx.x : (blockIdx.x - HB);
    for (int i = t; i < W; i += HT) lcnt[i] = 0;
    __syncthreads();
    const int e0 = b * epb;
    const int e1 = min(nE, e0 + epb);
    if (is_dst) {
        for (int e = e0 + t; e < e1; e += HT) {
            const int d = dst[e];
            const unsigned sh = (unsigned)(d & 3) * 8u;
            const unsigned old = atomicAdd(&lcnt[d >> 2], 1u << sh);
            lrank[e] = (unsigned char)((old >> sh) & 0xffu);
        }
    } else {
        for (int e = e0 + t; e < e1; e += HT) {
            const int s = src[e];
            atomicAdd(&lcnt[s >> 2], 1u << ((unsigned)(s & 3) * 8u));
        }
    }
    __syncthreads();
    unsigned* g = (is_dst ? partial_in : partial_out) + (size_t)b * W;
    for (int i = t; i < W; i += HT) g[i] = lcnt[i];
}

// ---------------------------------------------------------------------------
// Reduce 128 partials per node-word + (dst role) block-local exclusive scan
// (R9-proven, byte-identical). dst blocks: offs_in, cnt_in, rpp, bsum.
// out blocks: cnt_out. Block = 256 threads covers 1024 consecutive nodes.
// ---------------------------------------------------------------------------
__global__ __launch_bounds__(256) void reduce_scan_kernel(const unsigned* __restrict__ partial_out,
                                                          const unsigned* __restrict__ partial_in,
                                                          unsigned* __restrict__ offs_in,
                                                          int* __restrict__ cnt_out,
                                                          int* __restrict__ cnt_in,
                                                          int* __restrict__ rpp,
                                                          int* __restrict__ bsum,
                                                          int W, int n, int nbW) {
    const int t = threadIdx.x;
    if ((int)blockIdx.x >= nbW) {
        // ---- out-degree role (no barriers) ----
        const int w = (blockIdx.x - nbW) * 256 + t;
        if (w >= W) return;
        unsigned run = 0;
#pragma unroll 16
        for (int b = 0; b < HB; ++b) run += partial_out[(size_t)b * W + w];
        const int n0 = w * 4;
        const int4 c4 = make_int4((int)(run & 0xffu), (int)((run >> 8) & 0xffu),
                                  (int)((run >> 16) & 0xffu), (int)((run >> 24) & 0xffu));
        if (n0 + 3 < n) {
            *(int4*)&cnt_out[n0] = c4;
        } else {
            const int* cp = &c4.x;
            for (int i = 0; i < 4 && n0 + i < n; ++i) cnt_out[n0 + i] = cp[i];
        }
        return;
    }

    // ---- in-degree role + block scan (all threads alive for barriers) ----
    __shared__ int ws[4];
    const int w = blockIdx.x * 256 + t;
    unsigned run = 0;
    if (w < W) {
#pragma unroll 16
        for (int b = 0; b < HB; ++b) {
            const unsigned c = partial_in[(size_t)b * W + w];
            offs_in[(size_t)b * W + w] = run;
            run += c;
        }
    }
    const int n0 = w * 4;
    int c0 = (int)(run & 0xffu), c1 = (int)((run >> 8) & 0xffu);
    int c2 = (int)((run >> 16) & 0xffu), c3 = (int)((run >> 24) & 0xffu);
    if (n0 >= n)          { c0 = 0; c1 = 0; c2 = 0; c3 = 0; }
    else if (n0 + 1 >= n) { c1 = 0; c2 = 0; c3 = 0; }
    else if (n0 + 2 >= n) { c2 = 0; c3 = 0; }
    else if (n0 + 3 >= n) { c3 = 0; }

    if (w < W) {
        const int4 c4 = make_int4(c0, c1, c2, c3);
        if (n0 + 3 < n) {
            *(int4*)&cnt_in[n0] = c4;
        } else {
            const int* cp = &c4.x;
            for (int i = 0; i < 4 && n0 + i < n; ++i) cnt_in[n0 + i] = cp[i];
        }
    }

    // block-local exclusive scan over 1024 node counts
    const int lane = t & 63;
    const int wid = t >> 6;
    const int T = c0 + c1 + c2 + c3;
    int sincl = T;
#pragma unroll
    for (int off = 1; off < 64; off <<= 1) {
        int u = __shfl_up(sincl, off, 64);
        if (lane >= off) sincl += u;
    }
    if (lane == 63) ws[wid] = sincl;
    __syncthreads();
    int wbase = 0;
#pragma unroll
    for (int j = 0; j < 4; ++j) wbase += (j < wid) ? ws[j] : 0;
    const int excl = wbase + sincl - T;

    if (w < W && n0 < n) {
        const int4 r4 = make_int4(excl, excl + c0, excl + c0 + c1, excl + c0 + c1 + c2);
        if (n0 + 3 < n) {
            *(int4*)&rpp[n0] = r4;
        } else {
            const int* rp4 = &r4.x;
            for (int i = 0; i < 4 && n0 + i < n; ++i) rpp[n0 + i] = rp4[i];
        }
    }
    if (t == 255) bsum[blockIdx.x] = wbase + sincl;   // block total
}

// ---------------------------------------------------------------------------
// FUSED: GEMM1 + CSR fill + finalize (3 roles, one dispatch).
// gemm role [0,nGemm): y1 = (x@W1)*osc -> fp16, osc computed directly from
//   cnt_out (identical numerics to R9's onorm[row] read).
// fill role [nGemm,nGemm+fg): derives final rp from rpp+bpref (R7-proven),
//   scatters srcs_sorted.
// finalize role [nGemm+fg,..): rp = rpp + prefix(bsum), onorm, inorm,
//   rp[n]=E — for agg1..gemm3.
// ---------------------------------------------------------------------------
__global__ __launch_bounds__(1024) void gemm1_fill_finalize_kernel(
    const float* __restrict__ x, const _Float16* __restrict__ wt,
    const int* __restrict__ cnt_out, const int* __restrict__ cnt_in,
    __half* __restrict__ y1, int nrows,
    const int* __restrict__ src, const int* __restrict__ dst,
    const unsigned char* __restrict__ lrank, const unsigned* __restrict__ offs_in,
    const int* __restrict__ rpp, const int* __restrict__ bsum,
    int* __restrict__ rp, float* __restrict__ onorm, float* __restrict__ inorm,
    int* __restrict__ srcs_sorted,
    int nE, int epb, int W, int nGemmBlocks, int fg, int n, int nb) {
    __shared__ _Float16 sA[128 * 136];
    __shared__ _Float16 sB[128 * 136];
    const int t = threadIdx.x;

    if ((int)blockIdx.x >= nGemmBlocks + fg) {
        // ---- finalize role ----
        __shared__ int prefix_s;
        const int blk = blockIdx.x - nGemmBlocks - fg;
        if (t < 64) {
            int v = (t < nb && t < blk) ? bsum[t] : 0;
#pragma unroll
            for (int off = 1; off < 64; off <<= 1) v += __shfl_xor(v, off, 64);
            if (t == 0) prefix_s = v;
        }
        __syncthreads();
        const int i = blk * 1024 + t;
        if (i < n) {
            rp[i] = rpp[i] + prefix_s;
            onorm[i] = rsqrtf(fmaxf((float)cnt_out[i], 1.0f));
            inorm[i] = rsqrtf(fmaxf((float)cnt_in[i], 1.0f));
        }
        if (blk == 0 && t == 0) rp[n] = nE;
        return;
    }

    if ((int)blockIdx.x >= nGemmBlocks) {
        // ---- fill role: one edge per thread; derives rp itself ----
        __shared__ int bpref[64];    // inclusive scan of bsum
        if (t < 64) {
            int v = (t < nb) ? bsum[t] : 0;
            const int lane = t;
#pragma unroll
            for (int off = 1; off < 64; off <<= 1) {
                int u = __shfl_up(v, off, 64);
                if (lane >= off) v += u;
            }
            bpref[t] = v;
        }
        __syncthreads();
        const int e = (blockIdx.x - nGemmBlocks) * 1024 + t;
        if (e < nE) {
            const int d = dst[e];
            const int b = e / epb;
            const unsigned off =
                (offs_in[(size_t)b * W + (d >> 2)] >> ((unsigned)(d & 3) * 8u)) & 0xffu;
            const int blkd = d >> 10;
            const int rpf = rpp[d] + (blkd ? bpref[blkd - 1] : 0);
            srcs_sorted[rpf + (int)off + (int)lrank[e]] = src[e];
        }
        return;
    }

    // ---- GEMM role: 128x128 tile, 16 waves ----
    const int row0 = blockIdx.x * 128;
    const int rr = t >> 4;      // 64 staging rows per pass
    const int c8 = t & 15;
#pragma unroll
    for (int pass = 0; pass < 2; ++pass) {
        const int row = pass * 64 + rr;
        *(float4*)&sB[row * 136 + c8 * 8] = *(const float4*)&wt[(size_t)row * D + c8 * 8];
        const int grow = row0 + row;
        float4 u0 = make_float4(0.f, 0.f, 0.f, 0.f);
        float4 u1 = u0;
        if (grow < nrows) {
            const float* ap = x + (size_t)grow * D + c8 * 8;
            u0 = ((const float4*)ap)[0];
            u1 = ((const float4*)ap)[1];
        }
        v8h hv;
        hv[0] = (_Float16)u0.x; hv[1] = (_Float16)u0.y;
        hv[2] = (_Float16)u0.z; hv[3] = (_Float16)u0.w;
        hv[4] = (_Float16)u1.x; hv[5] = (_Float16)u1.y;
        hv[6] = (_Float16)u1.z; hv[7] = (_Float16)u1.w;
        *(v8h*)&sA[row * 136 + c8 * 8] = hv;
    }
    __syncthreads();

    const int w = t >> 6;       // 16 waves
    const int lane = t & 63;
    const int m16 = lane & 15;
    const int quad = lane >> 4;
    const int rt = w >> 1;      // row-tile 0..7
    const int ch = w & 1;       // col half 0..1

    v4f c[4];
#pragma unroll
    for (int ct = 0; ct < 4; ++ct) c[ct] = (v4f){0.f, 0.f, 0.f, 0.f};

#pragma unroll
    for (int ks = 0; ks < 4; ++ks) {
        const v8h a = *(const v8h*)&sA[(rt * 16 + m16) * 136 + ks * 32 + quad * 8];
#pragma unroll
        for (int ct = 0; ct < 4; ++ct) {
            const v8h b = *(const v8h*)&sB[((ch * 4 + ct) * 16 + m16) * 136 + ks * 32 + quad * 8];
            c[ct] = __builtin_amdgcn_mfma_f32_16x16x32_f16(a, b, c[ct], 0, 0, 0);
        }
    }

#pragma unroll
    for (int r = 0; r < 4; ++r) {
        const int row = row0 + rt * 16 + quad * 4 + r;
        if (row < nrows) {
            const float osc = rsqrtf(fmaxf((float)cnt_out[row], 1.0f));   // == onorm[row]
#pragma unroll
            for (int ct = 0; ct < 4; ++ct) {
                const int col = (ch * 4 + ct) * 16 + m16;
                y1[(size_t)row * D + col] = __float2half(c[ct][r] * osc);
            }
        }
    }
}

// ---------------------------------------------------------------------------
// Aggregation v5 (R16/R19-proven, BYTE-IDENTICAL to the 237.7us config):
// row-major 256B wide gather, wave-per-node x4, 8-deep up-front issue,
// fma_mix accumulate. No launch_bounds min-waves; size_t indexing.
// ---------------------------------------------------------------------------
template <bool EPI>
__global__ __launch_bounds__(256) void aggregate_kernel(const __half* __restrict__ xh,
                                                        const float* __restrict__ onorm,
                                                        const float* __restrict__ inorm,
                                                        const float* __restrict__ bias,
                                                        const int* __restrict__ rp,
                                                        const int* __restrict__ srcs,
                                                        __half* __restrict__ agg, int n_nodes) {
    const int node = blockIdx.x * 4 + (threadIdx.x >> 6);
    const int lane = threadIdx.x & 63;
    const int rg = lane >> 4;       // edge slot 0..3
    const int c8 = lane & 15;       // 16B chunk within the 256B row
    if (node >= n_nodes) return;
    const int e0 = rp[node];
    const int e1 = rp[node + 1];
    int e = e0 + rg;

    float acc[8];
#pragma unroll
    for (int j = 0; j < 8; ++j) acc[j] = 0.f;

    // ---- first pass: 8-deep, all loads issued before any use ----
    bool pr[8];
#pragma unroll
    for (int k = 0; k < 8; ++k) pr[k] = (e + 4 * k) < e1;
    int s[8];
#pragma unroll
    for (int k = 0; k < 8; ++k) {
        s[k] = 0;
        if (pr[k]) s[k] = __builtin_nontemporal_load(srcs + e + 4 * k);
    }
    H8 v[8];
#pragma unroll
    for (int k = 0; k < 8; ++k)
        v[k] = ((const H8*)(xh + (size_t)s[k] * D))[c8];
#pragma unroll
    for (int k = 0; k < 8; ++k) {
        if (pr[k]) {
#pragma unroll
            for (int j = 0; j < 4; ++j) {
                acc[2 * j]     = fmaf(__low2float(v[k].h[j]),  1.0f, acc[2 * j]);
                acc[2 * j + 1] = fmaf(__high2float(v[k].h[j]), 1.0f, acc[2 * j + 1]);
            }
        }
    }
    e += 32;

    // ---- rare tail (deg > 32) ----
    while (__any(e < e1)) {
        bool q[4];
        int u[4];
#pragma unroll
        for (int k = 0; k < 4; ++k) {
            q[k] = (e + 4 * k) < e1;
            u[k] = 0;
            if (q[k]) u[k] = __builtin_nontemporal_load(srcs + e + 4 * k);
        }
        H8 w[4];
#pragma unroll
        for (int k = 0; k < 4; ++k)
            w[k] = ((const H8*)(xh + (size_t)u[k] * D))[c8];
#pragma unroll
        for (int k = 0; k < 4; ++k) {
            if (q[k]) {
#pragma unroll
                for (int j = 0; j < 4; ++j) {
                    acc[2 * j]     = fmaf(__low2float(w[k].h[j]),  1.0f, acc[2 * j]);
                    acc[2 * j + 1] = fmaf(__high2float(w[k].h[j]), 1.0f, acc[2 * j + 1]);
                }
            }
        }
        e += 16;
    }

    float r[8];
#pragma unroll
    for (int j = 0; j < 8; ++j) r[j] = acc[j];
#pragma unroll
    for (int off = 16; off < 64; off <<= 1)    // reduce over the 4 edge slots
#pragma unroll
        for (int j = 0; j < 8; ++j) r[j] += __shfl_xor(r[j], off, 64);

    if (rg == 0) {
        if (EPI) {
            const float inm = inorm[node];
            const float onm = onorm[node];
            const float4 bv0 = ((const float4*)bias)[c8 * 2];
            const float4 bv1 = ((const float4*)bias)[c8 * 2 + 1];
            const float* bp0 = &bv0.x;
            const float* bp1 = &bv1.x;
#pragma unroll
            for (int j = 0; j < 4; ++j) {
                r[j]     = fmaxf(fmaf(r[j],     inm, bp0[j]), 0.f) * onm;
                r[j + 4] = fmaxf(fmaf(r[j + 4], inm, bp1[j]), 0.f) * onm;
            }
        }
        H8 h;
#pragma unroll
        for (int j = 0; j < 4; ++j) h.h[j] = __floats2half2_rn(r[2 * j], r[2 * j + 1]);
        ((H8*)(agg + (size_t)node * D))[c8] = h;
    }
}

// ---------------------------------------------------------------------------
// MFMA GEMM for layers 2/3 (R9-proven, byte-identical). 128x128 tile, fp16
// operands, fp32 acc. Epilogue: FULL(*inorm+bias), RELU, OSCALE, OUT16.
// ---------------------------------------------------------------------------
template <bool FULL, bool RELU, bool OSCALE, bool OUT16>
__global__ __launch_bounds__(256) void gemm_mfma_kernel(const __half* __restrict__ Ah,
                                                        const _Float16* __restrict__ Wt,
                                                        const float* __restrict__ bias,
                                                        const float* __restrict__ inorm,
                                                        const float* __restrict__ onorm,
                                                        void* __restrict__ outv, int nrows) {
    __shared__ _Float16 sA[128 * 136];
    __shared__ _Float16 sB[128 * 136];
    const int t = threadIdx.x;
    const int row0 = blockIdx.x * 128;
    const int rr = t >> 4;
    const int c8 = t & 15;

#pragma unroll
    for (int pass = 0; pass < 8; ++pass) {
        const int row = pass * 16 + rr;
        *(float4*)&sB[row * 136 + c8 * 8] = *(const float4*)&Wt[(size_t)row * D + c8 * 8];
        const int grow = row0 + row;
        float4 v = make_float4(0.f, 0.f, 0.f, 0.f);
        if (grow < nrows)
            v = *(const float4*)((const _Float16*)Ah + (size_t)grow * D + c8 * 8);
        *(float4*)&sA[row * 136 + c8 * 8] = v;
    }
    __syncthreads();

    const int w = t >> 6;
    const int lane = t & 63;
    const int m16 = lane & 15;
    const int quad = lane >> 4;

    v4f c[2][8];
#pragma unroll
    for (int rt = 0; rt < 2; ++rt)
#pragma unroll
        for (int ct = 0; ct < 8; ++ct) c[rt][ct] = (v4f){0.f, 0.f, 0.f, 0.f};

#pragma unroll
    for (int ks = 0; ks < 4; ++ks) {
        v8h afr[2], bfr[8];
#pragma unroll
        for (int rt = 0; rt < 2; ++rt)
            afr[rt] = *(const v8h*)&sA[(w * 32 + rt * 16 + m16) * 136 + ks * 32 + quad * 8];
#pragma unroll
        for (int ct = 0; ct < 8; ++ct)
            bfr[ct] = *(const v8h*)&sB[(ct * 16 + m16) * 136 + ks * 32 + quad * 8];
#pragma unroll
        for (int rt = 0; rt < 2; ++rt)
#pragma unroll
            for (int ct = 0; ct < 8; ++ct)
                c[rt][ct] = __builtin_amdgcn_mfma_f32_16x16x32_f16(afr[rt], bfr[ct], c[rt][ct], 0, 0, 0);
    }

#pragma unroll
    for (int rt = 0; rt < 2; ++rt) {
#pragma unroll
        for (int r = 0; r < 4; ++r) {
            const int row = row0 + w * 32 + rt * 16 + quad * 4 + r;
            if (row < nrows) {
                const float inm = FULL ? inorm[row] : 1.0f;
                const float osc = OSCALE ? onorm[row] : 1.0f;
#pragma unroll
                for (int ct = 0; ct < 8; ++ct) {
                    const int col = ct * 16 + m16;
                    float v = c[rt][ct][r];
                    if (FULL) v = fmaf(v, inm, bias[col]);
                    if (RELU) v = fmaxf(v, 0.f);
                    if (OSCALE) v *= osc;
                    if (OUT16) ((__half*)outv)[(size_t)row * D + col] = __float2half(v);
                    else       ((float*)outv)[(size_t)row * D + col] = v;
                }
            }
        }
    }
}

// ---------------------------------------------------------------------------
// Host launch
// ---------------------------------------------------------------------------
extern "C" void kernel_launch(void* const* d_in, const int* in_sizes, int n_in,
                              void* d_out, int out_size, void* d_ws, size_t ws_size,
                              hipStream_t stream) {
    const float* x   = (const float*)d_in[0];
    const int*   src = (const int*)d_in[1];
    const int*   dst = (const int*)d_in[2];
    const float* W1  = (const float*)d_in[3];
    const float* b1  = (const float*)d_in[4];
    const float* W2  = (const float*)d_in[5];
    const float* b2  = (const float*)d_in[6];
    const float* W3  = (const float*)d_in[7];
    const float* b3  = (const float*)d_in[8];

    const int N = in_sizes[0] / D;   // 50000
    const int E = in_sizes[1];       // 800000

    char* p = (char*)d_ws;
    auto alloc = [&](size_t bytes) -> void* {
        void* r = (void*)p;
        p += (bytes + 255) & ~(size_t)255;
        return r;
    };
    int*           cnt_out = (int*)alloc((size_t)N * 4);
    int*           cnt_in  = (int*)alloc((size_t)N * 4);
    int*           rp      = (int*)alloc((size_t)(N + 1) * 4);
    int*           rpp     = (int*)alloc((size_t)(N + 1) * 4);
    int*           bsum    = (int*)alloc(1024 * 4);
    float*         onorm   = (float*)alloc((size_t)N * 4);
    float*         inorm   = (float*)alloc((size_t)N * 4);
    int*           srcs    = (int*)alloc((size_t)E * 4);
    unsigned char* lrank   = (unsigned char*)alloc((size_t)E);
    _Float16*      wt      = (_Float16*)alloc((size_t)3 * D * D * 2);
    __half*        hbuf0   = (__half*)alloc((size_t)N * D * 2);  // y1, then h2
    __half*        hbuf1   = (__half*)alloc((size_t)N * D * 2);  // h1
    char*          scratch = (char*)alloc((size_t)3 * HB * ((N + 3) / 4) * 4);  // 19.2MB

    const int W = (N + 3) / 4;              // 12500 packed histogram words
    const int epb = (E + HB - 1) / HB;      // 6250 edges per histogram block
    unsigned* partial_in  = (unsigned*)scratch;
    unsigned* partial_out = partial_in + (size_t)HB * W;
    unsigned* offs_in     = partial_out + (size_t)HB * W;
    __half*   abuf        = (__half*)scratch;                  // a2, a3 (fp16)
    float*    outf        = (float*)d_out;

    const int nb = (N + 1023) / 1024;       // 49
    const int nbW = (W + 255) / 256;        // 49 (same 1024-node granule as nb)
    const int gemmGrid = (N + 127) / 128;   // 391
    const int fillGrid = (E + 1023) / 1024; // 782
    const int aggGrid = (N + 3) / 4;        // 12500

    // 1) hist + W-prep merged; no global atomics, no memset
    hist_kernel<<<2 * HB + 3, HT, 0, stream>>>(src, dst, partial_out, partial_in, lrank,
                                               W1, W2, W3, wt, E, W, epb);
    // 2) reduce partials + block-local scan (rpp, bsum) — merged
    reduce_scan_kernel<<<2 * nbW, 256, 0, stream>>>(partial_out, partial_in, offs_in,
                                                    cnt_out, cnt_in, rpp, bsum, W, N, nbW);
    // 3) GEMM1 (osc from cnt_out) || CSR fill (self-derived rp) || finalize
    gemm1_fill_finalize_kernel<<<gemmGrid + fillGrid + nb, 1024, 0, stream>>>(
        x, wt, cnt_out, cnt_in, hbuf0, N,
        src, dst, lrank, offs_in, rpp, bsum, rp, onorm, inorm, srcs,
        E, epb, W, gemmGrid, fillGrid, N, nb);

    // 4) Layer 1 aggregate + full epilogue -> h1 fp16
    aggregate_kernel<true><<<aggGrid, 256, 0, stream>>>(
        hbuf0, onorm, inorm, b1, rp, srcs, hbuf1, N);
    // 5-6) Layer 2: a2 = agg(h1) fp16; h2 = relu((a2@W2)*inorm+b2)*onorm -> fp16
    aggregate_kernel<false><<<aggGrid, 256, 0, stream>>>(
        hbuf1, onorm, inorm, b2, rp, srcs, abuf, N);
    gemm_mfma_kernel<true, true, true, true><<<gemmGrid, 256, 0, stream>>>(
        abuf, wt + (size_t)D * D, b2, inorm, onorm, hbuf0, N);
    // 7-8) Layer 3: a3 = agg(h2) fp16; out = (a3@W3)*inorm+b3 -> fp32 d_out
    aggregate_kernel<false><<<aggGrid, 256, 0, stream>>>(
        hbuf0, onorm, inorm, b3, rp, srcs, abuf, N);
    gemm_mfma_kernel<true, false, false, false><<<gemmGrid, 256, 0, stream>>>(
        abuf, wt + (size_t)2 * D * D, b3, inorm, onorm, outf, N);
}